// Round 1
// 507.242 us; speedup vs baseline: 1.4008x; 1.4008x over previous
//
#include <hip/hip_runtime.h>
#include <hip/hip_bf16.h>
#include <stdint.h>

// GRU layer: B=32, L=48, N=325, D=128. BN=10400 independent sequences, scan over L.
// Each 512-thread block owns 48 sequences and iterates all 48 timesteps locally:
// weights live in registers as MFMA B-fragments (loaded once), h is fp32 in regs
// for the elementwise update and bf16 in (double-buffered) LDS for the recurrent
// GEMM. bf16 MFMA 16x16x32.
//
// v2 change: X is staged global->LDS via __builtin_amdgcn_global_load_lds
// (zero-VGPR async DMA), double-buffered ONE TIMESTEP AHEAD. v1 held 12 floatx8
// X loads in VGPRs (96 regs in flight at a 124-reg budget), which serialized the
// loads into few-at-a-time batches -> ~15k cyc/step of exposed HBM latency
// (MfmaUtil 9%, VALUBusy 15%, HBM 11%). The DMA prefetch for step l+1 issues at
// the top of step l and completes under the step's compute; the __syncthreads
// vmcnt drain at the end of the step guarantees visibility for l+1.

constexpr int Bdim = 32;
constexpr int Ldim = 48;
constexpr int Nseq = 325;
constexpr int Ddim = 128;
constexpr int BN   = Bdim * Nseq;          // 10400
constexpr int MT   = 48;                   // sequences per block (3 m-tiles of 16)
constexpr int NBLK = (BN + MT - 1) / MT;   // 217 (<256 -> all blocks co-resident, no tail)
constexpr int RS   = 136;                  // h row stride bf16 (68 dwords == 4 mod 32: conflict-free b128 frag reads)
constexpr int XR32 = 528;                  // fp32 X row stride bytes (132 floats == 4 mod 32: conflict-free)
constexpr int XR16 = 272;                  // bf16 X row stride bytes (136 bf16 = 68 dwords)
constexpr int HBUF_B = 2 * MT * RS * 2;        // 26112 B
constexpr int SMEM_B = HBUF_B + 2 * MT * XR32; // 76800 B  (< 160 KiB/CU)

typedef __bf16 bf16;
typedef __bf16 bf16x4 __attribute__((ext_vector_type(4)));
typedef __bf16 bf16x8 __attribute__((ext_vector_type(8)));
typedef float  floatx4 __attribute__((ext_vector_type(4)));
typedef float  floatx8 __attribute__((ext_vector_type(8)));

__device__ __forceinline__ float fast_sigmoid(float x) {
    return __builtin_amdgcn_rcpf(1.f + __expf(-x));
}
__device__ __forceinline__ float fast_tanh(float x) {
    const float e = __expf(-2.f * __builtin_fabsf(x));
    const float t = (1.f - e) * __builtin_amdgcn_rcpf(1.f + e);
    return __builtin_copysignf(t, x);
}

// true  -> buffers are float32 (reference dtype)
// false -> buffers are bfloat16
__device__ __forceinline__ bool detect_f32(const void* wih) {
    const bf16* p = (const bf16*)wih;
    bool f32 = false;
#pragma unroll
    for (int i = 0; i < 128; i += 2) {
        const float v = __builtin_fabsf((float)p[i]);
        if (!(v <= 0.125f)) f32 = true;   // NaN also lands here
    }
    return f32;
}

template <bool F32>
__device__ __forceinline__ bf16x8 load8(const void* base, size_t off) {
    if constexpr (F32) {
        const floatx8 v = *(const floatx8*)((const float*)base + off);
        return __builtin_convertvector(v, bf16x8);
    } else {
        return *(const bf16x8*)((const bf16*)base + off);
    }
}
template <bool F32>
__device__ __forceinline__ float lds1(const void* base, int i) {
    if constexpr (F32) return ((const float*)base)[i];
    else               return (float)((const bf16*)base)[i];
}

// Async DMA: 4 B/lane (256 B/instruction). 4B width keeps each instruction
// inside one padded X row (16B/lane = 1024 B would span rows and break padding).
__device__ __forceinline__ void gload_lds4(const void* g, void* l) {
    __builtin_amdgcn_global_load_lds(
        (const __attribute__((address_space(1))) void*)g,
        (__attribute__((address_space(3))) void*)l, 4, 0, 0);
}

// A-fragment read from staged X in LDS: A[m=lane&15][k=q*8+j] for one kk tile.
template <bool F32>
__device__ __forceinline__ bf16x8 xfrag(const char* xb, int row, int kbase) {
    if constexpr (F32) {
        const float* p = (const float*)(xb + row * XR32) + kbase;
        const floatx4 a = *(const floatx4*)p;
        const floatx4 b = *(const floatx4*)(p + 4);
        const bf16x4 lo = __builtin_convertvector(a, bf16x4);
        const bf16x4 hi = __builtin_convertvector(b, bf16x4);
        return __builtin_shufflevector(lo, hi, 0, 1, 2, 3, 4, 5, 6, 7);
    } else {
        return *(const bf16x8*)((const bf16*)(xb + row * XR16) + kbase);
    }
}

template <bool F32>
__device__ __forceinline__ void gru_body(
    const void* __restrict__ X, const void* __restrict__ Wih,
    const void* __restrict__ Whh, const void* __restrict__ bih,
    const void* __restrict__ bhh, void* __restrict__ out,
    char* __restrict__ smem)
{
    const int tid  = threadIdx.x;
    const int wave = tid >> 6;       // 0..7 : owns d-cols [wave*16, wave*16+16)
    const int lane = tid & 63;
    const int l16  = lane & 15;
    const int q    = lane >> 4;      // quad 0..3
    const int t0   = blockIdx.x * MT;
    const int dcol = wave * 16 + l16;

    bf16* hbuf = (bf16*)smem;                 // [2][MT*RS]
    char* xbuf = smem + HBUF_B;               // [2][MT * XROWB]
    constexpr int XROWB   = F32 ? XR32 : XR16;
    constexpr int XBUF_B  = MT * XROWB;
    constexpr uint32_t lstride = (uint32_t)Nseq * Ddim * (F32 ? 4u : 2u); // X l-step bytes

    // Weight B-fragments (B[k=q*8+j][n=lane&15]) -> per lane one contiguous 8-elem run.
    bf16x8 wih_f[3][4], whh_f[3][4];
#pragma unroll
    for (int g = 0; g < 3; ++g) {
        const size_t rowoffw = (size_t)(g * 128 + dcol) * Ddim + q * 8;
#pragma unroll
        for (int kk = 0; kk < 4; ++kk) {
            wih_f[g][kk] = load8<F32>(Wih, rowoffw + kk * 32);
            whh_f[g][kk] = load8<F32>(Whh, rowoffw + kk * 32);
        }
    }

    const float bias_r  = lds1<F32>(bih, dcol)       + lds1<F32>(bhh, dcol);
    const float bias_z  = lds1<F32>(bih, 128 + dcol) + lds1<F32>(bhh, 128 + dcol);
    const float bias_in = lds1<F32>(bih, 256 + dcol);
    const float bias_hn = lds1<F32>(bhh, 256 + dcol);

    // Per-lane global byte offsets for the 6 X rows this wave stages (l=0 term).
    const int srow0 = wave * 6;
    const char* Xc = (const char*)X;
    uint32_t rowoff[6];
#pragma unroll
    for (int i = 0; i < 6; ++i) {
        int t = t0 + srow0 + i;
        if (t >= BN) t = BN - 1;               // clamp: garbage rows computed, stores masked
        const int b = t / Nseq;
        const int n = t - b * Nseq;
        rowoff[i] = (((uint32_t)b * (Ldim * Nseq) + (uint32_t)n) * Ddim) * (F32 ? 4u : 2u)
                  + ((uint32_t)lane << 2);     // + lane*4 B (DMA reads 4 B/lane)
    }

    // Issue the 6 (bf16) / 12 (fp32) DMA instructions for one timestep's X tile.
    auto stage = [&](char* xb, uint32_t loff) {
#pragma unroll
        for (int i = 0; i < 6; ++i) {
            const char* g = Xc + rowoff[i] + loff;
            char* d = xb + (srow0 + i) * XROWB;  // wave-uniform LDS base (required)
            gload_lds4(g, d);
            if constexpr (F32) gload_lds4(g + 256, d + 256);
        }
    };

    for (int i = tid; i < MT * RS; i += 512) hbuf[i] = (bf16)0.f;
    stage(xbuf, 0);                            // prefetch l=0
    floatx4 hreg[3];
#pragma unroll
    for (int mt = 0; mt < 3; ++mt) hreg[mt] = floatx4{0.f, 0.f, 0.f, 0.f};
    __syncthreads();                           // drains vmcnt -> l=0 tile resident

    int cur = 0;
    for (int l = 0; l < Ldim; ++l) {
        const char* xc = xbuf + cur * XBUF_B;
        const bf16* hc = hbuf + cur * (MT * RS);

        // 1) gi A-fragments from staged LDS (reads of xbuf[cur] BEFORE new DMA issue,
        //    so no alias-ordering wait can stall them).
        bf16x8 xf[3][4];
#pragma unroll
        for (int mt = 0; mt < 3; ++mt)
#pragma unroll
            for (int kk = 0; kk < 4; ++kk)
                xf[mt][kk] = xfrag<F32>(xc, mt * 16 + l16, kk * 32 + q * 8);

        // 2) Prefetch next timestep's X into the other buffer; latency hides under
        //    the two GEMMs + elementwise below, drained by the end-of-step barrier.
        if (l + 1 < Ldim) stage(xbuf + (cur ^ 1) * XBUF_B, (uint32_t)(l + 1) * lstride);

        floatx4 acc_r[3], acc_z[3], acc_in[3], acc_hn[3];
#pragma unroll
        for (int mt = 0; mt < 3; ++mt) {
            acc_r[mt]  = floatx4{bias_r,  bias_r,  bias_r,  bias_r};
            acc_z[mt]  = floatx4{bias_z,  bias_z,  bias_z,  bias_z};
            acc_in[mt] = floatx4{bias_in, bias_in, bias_in, bias_in};
            acc_hn[mt] = floatx4{bias_hn, bias_hn, bias_hn, bias_hn};
        }

        // 3) gh GEMM: h_prev (LDS bf16) @ Whh^T
#pragma unroll
        for (int kk = 0; kk < 4; ++kk) {
#pragma unroll
            for (int mt = 0; mt < 3; ++mt) {
                const bf16x8 af = *(const bf16x8*)&hc[(mt * 16 + l16) * RS + kk * 32 + q * 8];
                acc_r[mt]  = __builtin_amdgcn_mfma_f32_16x16x32_bf16(af, whh_f[0][kk], acc_r[mt],  0, 0, 0);
                acc_z[mt]  = __builtin_amdgcn_mfma_f32_16x16x32_bf16(af, whh_f[1][kk], acc_z[mt],  0, 0, 0);
                acc_hn[mt] = __builtin_amdgcn_mfma_f32_16x16x32_bf16(af, whh_f[2][kk], acc_hn[mt], 0, 0, 0);
            }
        }
        // 4) gi GEMM: x_l @ Wih^T (A-frags already in registers)
#pragma unroll
        for (int kk = 0; kk < 4; ++kk) {
#pragma unroll
            for (int mt = 0; mt < 3; ++mt) {
                acc_r[mt]  = __builtin_amdgcn_mfma_f32_16x16x32_bf16(xf[mt][kk], wih_f[0][kk], acc_r[mt],  0, 0, 0);
                acc_z[mt]  = __builtin_amdgcn_mfma_f32_16x16x32_bf16(xf[mt][kk], wih_f[1][kk], acc_z[mt],  0, 0, 0);
                acc_in[mt] = __builtin_amdgcn_mfma_f32_16x16x32_bf16(xf[mt][kk], wih_f[2][kk], acc_in[mt], 0, 0, 0);
            }
        }

        // 5) GRU update in registers (C layout: row = q*4 + r, col = dcol).
        const int nxt = cur ^ 1;
        bf16* hn = hbuf + nxt * (MT * RS);
#pragma unroll
        for (int mt = 0; mt < 3; ++mt) {
            floatx4 hnew;
#pragma unroll
            for (int r = 0; r < 4; ++r) {
                const float rg = fast_sigmoid(acc_r[mt][r]);
                const float zg = fast_sigmoid(acc_z[mt][r]);
                const float ng = fast_tanh(acc_in[mt][r] + rg * acc_hn[mt][r]);
                const float h  = (1.f - zg) * ng + zg * hreg[mt][r];
                hnew[r] = h;
                const int m = mt * 16 + q * 4 + r;
                hn[m * RS + dcol] = (bf16)h;
                const int t = t0 + m;
                if (t < BN) {
                    const size_t oi = ((size_t)l * BN + t) * Ddim + dcol;
                    if constexpr (F32) ((float*)out)[oi] = h;
                    else               ((bf16*)out)[oi]  = (bf16)h;
                }
            }
            hreg[mt] = hnew;
        }
        __syncthreads();   // drains vmcnt+lgkm: out stores, h writes, next-X DMA all land
        cur = nxt;
    }
}

__global__ __launch_bounds__(512, 2) void gru_rnn_kernel(
    const void* __restrict__ X, const void* __restrict__ Wih,
    const void* __restrict__ Whh, const void* __restrict__ bih,
    const void* __restrict__ bhh, void* __restrict__ out)
{
    __shared__ __align__(16) char smem[SMEM_B];
    if (detect_f32(Wih)) gru_body<true >(X, Wih, Whh, bih, bhh, out, smem);
    else                 gru_body<false>(X, Wih, Whh, bih, bhh, out, smem);
}

extern "C" void kernel_launch(void* const* d_in, const int* in_sizes, int n_in,
                              void* d_out, int out_size, void* d_ws, size_t ws_size,
                              hipStream_t stream) {
    hipLaunchKernelGGL(gru_rnn_kernel, dim3(NBLK), dim3(512), 0, stream,
                       d_in[0], d_in[1], d_in[2], d_in[3], d_in[4], d_out);
}

// Round 3
// 454.749 us; speedup vs baseline: 1.5625x; 1.1154x over previous
//
#include <hip/hip_runtime.h>
#include <hip/hip_bf16.h>
#include <stdint.h>

// GRU layer: B=32, L=48, N=325, D=128. BN=10400 independent sequences, scan over L.
// Each 512-thread block owns 48 sequences and iterates all 48 timesteps locally:
// weights live in registers as MFMA B-fragments (loaded once), h is fp32 in regs
// for the elementwise update and bf16 in (double-buffered) LDS for the recurrent
// GEMM. bf16 MFMA 16x16x32.
//
// v3 changes (v2 was global_load_lds DMA staging of raw fp32 X):
//  - X is register-staged one step ahead with fp32->bf16 conversion at STAGE time:
//    6 global_load_dwordx2 + 6 cvt_pk + 6 ds_write_b32 per wave per step. This
//    halves the X LDS-read traffic (12 bf16 b128 reads instead of 24 fp32 reads
//    per wave per step), converts each X element once per block instead of once
//    per consuming lane (48 -> 6 cvt_pk/wave/step), and halves X LDS footprint.
//    VGPR cost is free: occupancy is pinned at 2 waves/SIMD by the 217-block grid.
//  - No vmem ops need ordering at the step barrier anymore (DMA gone, output
//    stores need no ordering), so __syncthreads (which drains vmcnt(0), exposing
//    store write-ack latency every step) is replaced by lgkmcnt(0) + s_barrier.
//  - Output store addresses are incremental (base += BN*D*esz per step; the r
//    offset folds into the store-immediate).
// (Round-2 bench was an infra container failure, no counters; resubmitted as-is.)

constexpr int Bdim = 32;
constexpr int Ldim = 48;
constexpr int Nseq = 325;
constexpr int Ddim = 128;
constexpr int BN   = Bdim * Nseq;          // 10400
constexpr int MT   = 48;                   // sequences per block (3 m-tiles of 16)
constexpr int NBLK = (BN + MT - 1) / MT;   // 217 (<256 -> all blocks co-resident)
constexpr int RS   = 136;                  // h row stride, bf16 elems (68 dwords == 4 mod 32)
constexpr int XR   = 272;                  // x row stride BYTES (136 bf16, same alias pattern as h)
constexpr int HBUF_B = 2 * MT * RS * 2;    // 26112 B
constexpr int XBUF_B = MT * XR;            // 13056 B per buffer
constexpr int SMEM_B = HBUF_B + 2 * XBUF_B;// 52224 B

typedef __bf16 bf16;
typedef __bf16 bf16x2 __attribute__((ext_vector_type(2)));
typedef __bf16 bf16x8 __attribute__((ext_vector_type(8)));
typedef float  floatx2 __attribute__((ext_vector_type(2)));
typedef float  floatx4 __attribute__((ext_vector_type(4)));
typedef float  floatx8 __attribute__((ext_vector_type(8)));

__device__ __forceinline__ float fast_sigmoid(float x) {
    return __builtin_amdgcn_rcpf(1.f + __expf(-x));
}
__device__ __forceinline__ float fast_tanh(float x) {
    const float e = __expf(-2.f * __builtin_fabsf(x));
    const float t = (1.f - e) * __builtin_amdgcn_rcpf(1.f + e);
    return __builtin_copysignf(t, x);
}

// Barrier with LDS-visibility only: does NOT drain vmcnt, so output stores and
// prefetch loads stay in flight across steps. sched_barrier(0) fences keep the
// compiler from hoisting LDS ops across the inline-asm wait (rule #18).
__device__ __forceinline__ void sync_lds_only() {
    __builtin_amdgcn_sched_barrier(0);
    asm volatile("s_waitcnt lgkmcnt(0)" ::: "memory");
    __builtin_amdgcn_sched_barrier(0);
    __builtin_amdgcn_s_barrier();
    __builtin_amdgcn_sched_barrier(0);
}

// true  -> buffers are float32 (reference dtype)
// false -> buffers are bfloat16
__device__ __forceinline__ bool detect_f32(const void* wih) {
    const bf16* p = (const bf16*)wih;
    bool f32 = false;
#pragma unroll
    for (int i = 0; i < 128; i += 2) {
        const float v = __builtin_fabsf((float)p[i]);
        if (!(v <= 0.125f)) f32 = true;   // NaN also lands here
    }
    return f32;
}

template <bool F32>
__device__ __forceinline__ bf16x8 load8(const void* base, size_t off) {
    if constexpr (F32) {
        const floatx8 v = *(const floatx8*)((const float*)base + off);
        return __builtin_convertvector(v, bf16x8);
    } else {
        return *(const bf16x8*)((const bf16*)base + off);
    }
}
template <bool F32>
__device__ __forceinline__ float lds1(const void* base, int i) {
    if constexpr (F32) return ((const float*)base)[i];
    else               return (float)((const bf16*)base)[i];
}

template <bool F32>
__device__ __forceinline__ void gru_body(
    const void* __restrict__ X, const void* __restrict__ Wih,
    const void* __restrict__ Whh, const void* __restrict__ bih,
    const void* __restrict__ bhh, void* __restrict__ out,
    char* __restrict__ smem)
{
    const int tid  = threadIdx.x;
    const int wave = tid >> 6;       // 0..7 : owns d-cols [wave*16, wave*16+16)
    const int lane = tid & 63;
    const int l16  = lane & 15;
    const int q    = lane >> 4;      // quad 0..3
    const int t0   = blockIdx.x * MT;
    const int dcol = wave * 16 + l16;

    bf16* hbuf = (bf16*)smem;                 // [2][MT*RS]
    char* xbuf = smem + HBUF_B;               // [2][MT*XR] bf16 rows

    // Weight B-fragments (B[k=q*8+j][n=lane&15]) -> per lane one contiguous 8-elem run.
    bf16x8 wih_f[3][4], whh_f[3][4];
#pragma unroll
    for (int g = 0; g < 3; ++g) {
        const size_t rowoffw = (size_t)(g * 128 + dcol) * Ddim + q * 8;
#pragma unroll
        for (int kk = 0; kk < 4; ++kk) {
            wih_f[g][kk] = load8<F32>(Wih, rowoffw + kk * 32);
            whh_f[g][kk] = load8<F32>(Whh, rowoffw + kk * 32);
        }
    }

    const float bias_r  = lds1<F32>(bih, dcol)       + lds1<F32>(bhh, dcol);
    const float bias_z  = lds1<F32>(bih, 128 + dcol) + lds1<F32>(bhh, 128 + dcol);
    const float bias_in = lds1<F32>(bih, 256 + dcol);
    const float bias_hn = lds1<F32>(bhh, 256 + dcol);

    // --- X staging: this wave owns block-local rows [wave*6, wave*6+6).
    // Per row, each lane loads elems [2*lane, 2*lane+1] (dwordx2 fp32 / dword bf16),
    // converts to bf16 and ds_write_b32's them into the padded bf16 row.
    const int   srow0 = wave * 6;
    const char* Xc    = (const char*)X;
    const uint32_t lstride = (uint32_t)(Nseq * Ddim) * (F32 ? 4u : 2u);
    uint32_t rowoff[6];
#pragma unroll
    for (int i = 0; i < 6; ++i) {
        int t = t0 + srow0 + i;
        if (t >= BN) t = BN - 1;               // clamp: garbage rows computed, stores masked
        const int b = t / Nseq;
        const int n = t - b * Nseq;
        rowoff[i] = (uint32_t)(b * (Ldim * Nseq) + n) * Ddim * (F32 ? 4u : 2u)
                  + ((uint32_t)lane << (F32 ? 3 : 2));
    }

    floatx2  vf[6];
    uint32_t vb[6];
    auto stage_load = [&](int l) {
        const char* Xl = Xc + (uint32_t)l * lstride;
#pragma unroll
        for (int i = 0; i < 6; ++i) {
            if constexpr (F32) vf[i] = *(const floatx2*)(Xl + rowoff[i]);
            else               vb[i] = *(const uint32_t*)(Xl + rowoff[i]);
        }
    };
    auto stage_write = [&](char* xb) {
#pragma unroll
        for (int i = 0; i < 6; ++i) {
            uint32_t w;
            if constexpr (F32) {
                union { bf16x2 h; uint32_t u; } cv;
                cv.h = __builtin_convertvector(vf[i], bf16x2);
                w = cv.u;
            } else {
                w = vb[i];
            }
            *(uint32_t*)(xb + (srow0 + i) * XR + (lane << 2)) = w;
        }
    };

    // --- Output store bases (incremental; r-offset folds into store immediate).
    constexpr size_t esz = F32 ? 4 : 2;
    const size_t OSTEP = (size_t)BN * Ddim * esz;
    size_t obyte[3];
    bool   msk[3][4];
#pragma unroll
    for (int mt = 0; mt < 3; ++mt) {
        const int trow = t0 + mt * 16 + q * 4;
        obyte[mt] = ((size_t)trow * Ddim + dcol) * esz;
#pragma unroll
        for (int r = 0; r < 4; ++r) msk[mt][r] = (trow + r) < BN;
    }

    for (int i = tid; i < MT * RS; i += 512) hbuf[i] = (bf16)0.f;
    stage_load(0);
    stage_write(xbuf);
    floatx4 hreg[3];
#pragma unroll
    for (int mt = 0; mt < 3; ++mt) hreg[mt] = floatx4{0.f, 0.f, 0.f, 0.f};
    __syncthreads();                           // one-time full drain; l=0 tile resident

    int cur = 0;
    for (int l = 0; l < Ldim; ++l) {
        const char* xc = xbuf + cur * XBUF_B;
        const bf16* hc = hbuf + cur * (MT * RS);

        // 1) gi A-fragments from staged bf16 X in LDS.
        bf16x8 xf[3][4];
#pragma unroll
        for (int mt = 0; mt < 3; ++mt)
#pragma unroll
            for (int kk = 0; kk < 4; ++kk)
                xf[mt][kk] = *(const bf16x8*)(xc + (mt * 16 + l16) * XR + kk * 64 + q * 16);

        // 2) Issue next timestep's X loads into registers; the cvt at stage_write
        //    (end of step) is the first use, so the HBM latency hides under the
        //    GEMMs + elementwise. (Last iter re-loads l=47: L3-hit, discarded.)
        const int lp = (l + 1 < Ldim) ? (l + 1) : (Ldim - 1);
        stage_load(lp);

        floatx4 acc_r[3], acc_z[3], acc_in[3], acc_hn[3];
#pragma unroll
        for (int mt = 0; mt < 3; ++mt) {
            acc_r[mt]  = floatx4{bias_r,  bias_r,  bias_r,  bias_r};
            acc_z[mt]  = floatx4{bias_z,  bias_z,  bias_z,  bias_z};
            acc_in[mt] = floatx4{bias_in, bias_in, bias_in, bias_in};
            acc_hn[mt] = floatx4{bias_hn, bias_hn, bias_hn, bias_hn};
        }

        // 3) gh GEMM: h_prev (LDS bf16) @ Whh^T
#pragma unroll
        for (int kk = 0; kk < 4; ++kk) {
#pragma unroll
            for (int mt = 0; mt < 3; ++mt) {
                const bf16x8 af = *(const bf16x8*)&hc[(mt * 16 + l16) * RS + kk * 32 + q * 8];
                acc_r[mt]  = __builtin_amdgcn_mfma_f32_16x16x32_bf16(af, whh_f[0][kk], acc_r[mt],  0, 0, 0);
                acc_z[mt]  = __builtin_amdgcn_mfma_f32_16x16x32_bf16(af, whh_f[1][kk], acc_z[mt],  0, 0, 0);
                acc_hn[mt] = __builtin_amdgcn_mfma_f32_16x16x32_bf16(af, whh_f[2][kk], acc_hn[mt], 0, 0, 0);
            }
        }
        // 4) gi GEMM: x_l @ Wih^T (A-frags already in registers)
#pragma unroll
        for (int kk = 0; kk < 4; ++kk) {
#pragma unroll
            for (int mt = 0; mt < 3; ++mt) {
                acc_r[mt]  = __builtin_amdgcn_mfma_f32_16x16x32_bf16(xf[mt][kk], wih_f[0][kk], acc_r[mt],  0, 0, 0);
                acc_z[mt]  = __builtin_amdgcn_mfma_f32_16x16x32_bf16(xf[mt][kk], wih_f[1][kk], acc_z[mt],  0, 0, 0);
                acc_in[mt] = __builtin_amdgcn_mfma_f32_16x16x32_bf16(xf[mt][kk], wih_f[2][kk], acc_in[mt], 0, 0, 0);
            }
        }

        // 5) GRU update in registers (C layout: row = q*4 + r, col = dcol).
        const int nxt = cur ^ 1;
        bf16* hn = hbuf + nxt * (MT * RS);
#pragma unroll
        for (int mt = 0; mt < 3; ++mt) {
            floatx4 hnew;
#pragma unroll
            for (int r = 0; r < 4; ++r) {
                const float rg = fast_sigmoid(acc_r[mt][r]);
                const float zg = fast_sigmoid(acc_z[mt][r]);
                const float ng = fast_tanh(acc_in[mt][r] + rg * acc_hn[mt][r]);
                const float h  = ng + zg * (hreg[mt][r] - ng);   // (1-z)*ng + z*h
                hnew[r] = h;
                hn[(mt * 16 + q * 4 + r) * RS + dcol] = (bf16)h;
                if (msk[mt][r]) {
                    char* op = (char*)out + obyte[mt] + (size_t)(r * Ddim) * esz;
                    if constexpr (F32) *(float*)op = h;
                    else               *(bf16*)op  = (bf16)h;
                }
            }
            hreg[mt]  = hnew;
            obyte[mt] += OSTEP;
        }

        // 6) Convert + write the prefetched X tile into the other buffer.
        stage_write(xbuf + nxt * XBUF_B);

        // 7) LDS-only barrier: stores/loads in flight are NOT drained.
        sync_lds_only();
        cur = nxt;
    }
}

__global__ __launch_bounds__(512, 2) void gru_rnn_kernel(
    const void* __restrict__ X, const void* __restrict__ Wih,
    const void* __restrict__ Whh, const void* __restrict__ bih,
    const void* __restrict__ bhh, void* __restrict__ out)
{
    __shared__ __align__(16) char smem[SMEM_B];
    if (detect_f32(Wih)) gru_body<true >(X, Wih, Whh, bih, bhh, out, smem);
    else                 gru_body<false>(X, Wih, Whh, bih, bhh, out, smem);
}

extern "C" void kernel_launch(void* const* d_in, const int* in_sizes, int n_in,
                              void* d_out, int out_size, void* d_ws, size_t ws_size,
                              hipStream_t stream) {
    hipLaunchKernelGGL(gru_rnn_kernel, dim3(NBLK), dim3(512), 0, stream,
                       d_in[0], d_in[1], d_in[2], d_in[3], d_in[4], d_out);
}